// Round 12
// baseline (221.860 us; speedup 1.0000x reference)
//
#include <hip/hip_runtime.h>

#define D 256
#define CAP 128          // max stored neighbors/node; deg ~ Binom(320k,1e-4): mean 32, >15 sigma margin
#define ASTRIDE 280      // LDS agg row stride in bf16 (560 B -> bank rotation, ~free)
#define LN_EPS 1e-5f

typedef short short8 __attribute__((ext_vector_type(8)));
typedef float floatx4 __attribute__((ext_vector_type(4)));
typedef unsigned short u16x4 __attribute__((ext_vector_type(4)));

typedef const __attribute__((address_space(1))) void* gas_t;
typedef __attribute__((address_space(3))) void* las_t;

// s_waitcnt vmcnt(n), lgkm/exp don't-care
#define WAIT_VM(n) __builtin_amdgcn_s_waitcnt(((n) & 0xF) | (((n) >> 4) << 14) | (7 << 4) | (0xF << 8))

__device__ __forceinline__ u16x4 umax4(u16x4 a, u16x4 b) {
#if __has_builtin(__builtin_elementwise_max)
    return __builtin_elementwise_max(a, b);   // v_pk_max_u16 x2
#else
    u16x4 r;
    r.x = a.x > b.x ? a.x : b.x; r.y = a.y > b.y ? a.y : b.y;
    r.z = a.z > b.z ? a.z : b.z; r.w = a.w > b.w ? a.w : b.w;
    return r;
#endif
}

// fp32 -> bf16 round-to-nearest-even (finite inputs)
__device__ __forceinline__ unsigned short f2b(float f) {
    union { float f; unsigned int u; } x; x.f = f;
    unsigned int u = x.u + 0x7FFFu + ((x.u >> 16) & 1u);
    return (unsigned short)(u >> 16);
}

// A-fragment from fp32 source: 8 consecutive floats -> bf16x8 (same rounding
// as pre-conversion -> bitwise-identical results).
__device__ __forceinline__ short8 ldA_f32(const float* p) {
    const float4 a = *(const float4*)p;
    const float4 b = *(const float4*)(p + 4);
    short8 r;
    r[0] = (short)f2b(a.x); r[1] = (short)f2b(a.y);
    r[2] = (short)f2b(a.z); r[3] = (short)f2b(a.w);
    r[4] = (short)f2b(b.x); r[5] = (short)f2b(b.y);
    r[6] = (short)f2b(b.z); r[7] = (short)f2b(b.w);
    return r;
}

// GEMM half-K pass (relu kernel): hoist 4 A-frags + 16 B-frags before MFMAs.
#define GEMM_HALF(A_EXPR, WPTR, K0H)                                            \
    {                                                                           \
        short8 aF[4], bF[4][4];                                                 \
        _Pragma("unroll") for (int ks = 0; ks < 4; ks++)                        \
            aF[ks] = A_EXPR(K0H + ks * 32);                                     \
        _Pragma("unroll") for (int ks = 0; ks < 4; ks++)                        \
        _Pragma("unroll") for (int t = 0; t < 4; t++)                           \
            bF[ks][t] = *(const short8*)((WPTR) + t * 16 * D + (K0H) + ks * 32);\
        _Pragma("unroll") for (int ks = 0; ks < 4; ks++) {                      \
            acc[0] = __builtin_amdgcn_mfma_f32_16x16x32_bf16(aF[ks], bF[ks][0], acc[0], 0, 0, 0); \
            acc[1] = __builtin_amdgcn_mfma_f32_16x16x32_bf16(aF[ks], bF[ks][1], acc[1], 0, 0, 0); \
            acc[2] = __builtin_amdgcn_mfma_f32_16x16x32_bf16(aF[ks], bF[ks][2], acc[2], 0, 0, 0); \
            acc[3] = __builtin_amdgcn_mfma_f32_16x16x32_bf16(aF[ks], bF[ks][3], acc[3], 0, 0, 0); \
        }                                                                       \
    }

// ---------------- prep: weight conv + zero cnt + zero pad-row ----------------
__global__ __launch_bounds__(256) void prep_kernel(
    const float* __restrict__ w0, const float* __restrict__ w1,
    const float* __restrict__ w2, const float* __restrict__ w3,
    const float* __restrict__ w4, const float* __restrict__ w5,
    unsigned short* __restrict__ wb,
    int* __restrict__ cnt, unsigned short* __restrict__ mb, int N)
{
    const int blk = blockIdx.x;
    const int tid = threadIdx.x;
    if (blk < 384) {
        const int wsel = blk >> 6;
        const float* src;
        switch (wsel) {
            case 0: src = w0; break; case 1: src = w1; break;
            case 2: src = w2; break; case 3: src = w3; break;
            case 4: src = w4; break; default: src = w5; break;
        }
        const int idx = (blk & 63) * 1024 + tid * 4;
        const float4 v = *(const float4*)(src + idx);
        ushort4 o;
        o.x = f2b(v.x); o.y = f2b(v.y); o.z = f2b(v.z); o.w = f2b(v.w);
        *(ushort4*)(wb + (size_t)wsel * 65536 + idx) = o;
    } else if (blk < 424) {
        const int i = (blk - 384) * 256 + tid;
        if (i < N) cnt[i] = 0;
    } else {
        mb[(size_t)N * D + tid] = 0;   // pad row: max-identity for relu outputs
    }
}

// ---------------- mode-0 GEMM: 1-wave blocks, XCD-swizzled (+ scatter) -------
__global__ __launch_bounds__(64, 4) void gemm_relu(
    const float* __restrict__ Af, const unsigned short* __restrict__ Ab,
    const unsigned short* __restrict__ W,
    const float* __restrict__ bias, unsigned short* __restrict__ out_b, int nrow,
    const int* __restrict__ esrc, const int* __restrict__ edst,
    int* __restrict__ cnt, unsigned short* __restrict__ csr, int E, int ngemm)
{
    if ((int)blockIdx.x >= ngemm) {
        const int nsb = gridDim.x - ngemm;
        int i = ((int)blockIdx.x - ngemm) * 64 + threadIdx.x;
        const int stride = nsb * 64;
        for (; i < E; i += stride) {
            const int d = edst[i];
            const int pos = atomicAdd(&cnt[d], 1);
            if (pos < CAP) csr[(size_t)d * CAP + pos] = (unsigned short)esrc[i];
        }
        return;
    }

    // swizzle: a row-block's 4 col-tiles differ by 8 in blockIdx -> same XCD
    const int blk = blockIdx.x;
    const int g = blk >> 5;
    const int o = blk & 31;
    const int c = o >> 3;
    const int r = g * 8 + (o & 7);
    if (r >= nrow) return;

    const int lane = threadIdx.x;
    const int quad = lane >> 4;
    const int l16 = lane & 15;
    const int row0 = r * 16;
    const int col0 = c * 64;
    const int koff = quad * 8;

    floatx4 acc[4];
#pragma unroll
    for (int t = 0; t < 4; t++) acc[t] = (floatx4)(0.f);

    const unsigned short* aptr = Ab ? Ab + (size_t)(row0 + l16) * D + koff : nullptr;
    const float*          afp  = Af ? Af + (size_t)(row0 + l16) * D + koff : nullptr;
    const unsigned short* wptr = W + (size_t)(col0 + l16) * D + koff;
#define A_SRC(K) (Af ? ldA_f32(afp + (K)) : *(const short8*)(aptr + (K)))
    GEMM_HALF(A_SRC, wptr, 0)
    GEMM_HALF(A_SRC, wptr, 128)
#undef A_SRC

#pragma unroll
    for (int t = 0; t < 4; t++) {
        const float bcol = bias[col0 + t * 16 + l16];
#pragma unroll
        for (int rr = 0; rr < 4; rr++) {
            const int rg = row0 + quad * 4 + rr;
            const int col = col0 + t * 16 + l16;
            out_b[(size_t)rg * D + col] = f2b(fmaxf(acc[t][rr] + bcol, 0.f));
        }
    }
}

// ---------------- mode-1 GEMM, wave-specialized pool ------------------------
// 384 threads = 6 waves. Waves 0-1: GEMM phases (128 cols each, 8 MFMA tiles).
// Waves 2-5: R8-frozen async pool (4 dst rows each, 8 KB/wave in flight) —
// runs CONCURRENTLY with phase 0, so the gather hides the GEMM instead of
// serializing after it.
__global__ __launch_bounds__(384, 4) void gemm_ln_pool(
    const float* __restrict__ Af, const unsigned short* __restrict__ Ab,
    const unsigned short* __restrict__ Wself,
    const unsigned short* __restrict__ Wneigh,
    const unsigned short* __restrict__ mpool,
    const int* __restrict__ cnt, const unsigned short* __restrict__ csr,
    const float* __restrict__ bias,
    const float* __restrict__ gamma, const float* __restrict__ beta,
    unsigned short* __restrict__ out_b, float* __restrict__ out_f, int N)
{
    __shared__ unsigned short idxS[16][CAP];          // 4 KB
    __shared__ unsigned short gbuf[4][2][8][D];       // 32 KB (one slab per pool wave)
    __shared__ unsigned short aggS[16 * ASTRIDE];     // ~9 KB
    __shared__ float redS[2][16], redS2[2][16], muA[16], rsA[16];

    const int tid = threadIdx.x;
    const int wave = tid >> 6;
    const int lane = tid & 63;
    const int quad = lane >> 4;
    const int l16 = lane & 15;
    const int row0 = blockIdx.x * 16;
    const int koff = quad * 8;

    floatx4 acc[8];
#pragma unroll
    for (int t = 0; t < 8; t++) acc[t] = (floatx4)(0.f);

    if (wave >= 2) {
        // ================= pool waves (2..5): gather + max =================
        const int pw = wave - 2;          // 0..3
        const int rbase = pw * 4;
        const int half = lane >> 5;
        const int l32 = lane & 31;

        int degs[4];
#pragma unroll
        for (int rr = 0; rr < 4; rr++) degs[rr] = min(cnt[row0 + rbase + rr], CAP);
        int P = max(max(degs[0], degs[1]), max(degs[2], degs[3]));
        const int P2 = (P + 1) & ~1;                  // <= CAP
#pragma unroll
        for (int rr = 0; rr < 4; rr++) {
            const int rg = row0 + rbase + rr;
            for (int i = lane; i < P2; i += 64)
                idxS[rbase + rr][i] = (i < degs[rr]) ? csr[(size_t)rg * CAP + i]
                                                     : (unsigned short)N;
        }

        const int nb = P2 >> 1;           // bursts; each covers 2 neighbors per rr
        u16x4 mx[4];
#pragma unroll
        for (int rr = 0; rr < 4; rr++) mx[rr] = (u16x4)(0);

#define ISSUE_BURST(bi, buf)                                                    \
        {                                                                       \
            _Pragma("unroll") for (int rr = 0; rr < 4; rr++) {                  \
                const int jj = idxS[rbase + rr][2 * (bi) + half];               \
                const unsigned short* gp = mpool + (size_t)jj * D + l32 * 8;    \
                __builtin_amdgcn_global_load_lds(                               \
                    (gas_t)gp, (las_t)&gbuf[pw][buf][rr * 2][0], 16, 0, 0);     \
            }                                                                   \
        }

        if (nb > 0) ISSUE_BURST(0, 0);
        if (nb > 1) ISSUE_BURST(1, 1);
        for (int b = 0; b < nb; b++) {
            if (b + 1 < nb) WAIT_VM(4); else WAIT_VM(0);
            const int buf = b & 1;
#pragma unroll
            for (int rr = 0; rr < 4; rr++) {
                const u16x4 a0 = *(const u16x4*)&gbuf[pw][buf][rr * 2 + 0][lane * 4];
                const u16x4 a1 = *(const u16x4*)&gbuf[pw][buf][rr * 2 + 1][lane * 4];
                mx[rr] = umax4(mx[rr], umax4(a0, a1));
            }
            if (b + 2 < nb) ISSUE_BURST(b + 2, buf);
        }
#undef ISSUE_BURST
#pragma unroll
        for (int rr = 0; rr < 4; rr++)
            *(u16x4*)&aggS[(rbase + rr) * ASTRIDE + lane * 4] = mx[rr];
    } else {
        // ================= GEMM waves (0..1): phase 0 ======================
        const unsigned short* aptr = Ab ? Ab + (size_t)(row0 + l16) * D + koff : nullptr;
        const float*          afp  = Af ? Af + (size_t)(row0 + l16) * D + koff : nullptr;
        const unsigned short* wptr = Wself + (size_t)(wave * 128 + l16) * D + koff;
#pragma unroll
        for (int k0 = 0; k0 < D; k0 += 32) {
            const short8 av = Af ? ldA_f32(afp + k0) : *(const short8*)(aptr + k0);
            short8 bv[8];
#pragma unroll
            for (int t = 0; t < 8; t++)
                bv[t] = *(const short8*)(wptr + t * 16 * D + k0);
#pragma unroll
            for (int t = 0; t < 8; t++)
                acc[t] = __builtin_amdgcn_mfma_f32_16x16x32_bf16(av, bv[t], acc[t], 0, 0, 0);
        }
    }
    __syncthreads();

    if (wave < 2) {
        // ---- phase 1: agg @ Wneigh (A-fragments from LDS) ----
        const unsigned short* wptr = Wneigh + (size_t)(wave * 128 + l16) * D + koff;
#pragma unroll
        for (int k0 = 0; k0 < D; k0 += 32) {
            const short8 av = *(const short8*)&aggS[l16 * ASTRIDE + koff + k0];
            short8 bv[8];
#pragma unroll
            for (int t = 0; t < 8; t++)
                bv[t] = *(const short8*)(wptr + t * 16 * D + k0);
#pragma unroll
            for (int t = 0; t < 8; t++)
                acc[t] = __builtin_amdgcn_mfma_f32_16x16x32_bf16(av, bv[t], acc[t], 0, 0, 0);
        }

        // ---- bias + LN partials ----
#pragma unroll
        for (int t = 0; t < 8; t++) {
            const float bcol = bias[wave * 128 + t * 16 + l16];
#pragma unroll
            for (int r = 0; r < 4; r++) acc[t][r] += bcol;
        }
#pragma unroll
        for (int r = 0; r < 4; r++) {
            float s = 0.f, s2 = 0.f;
#pragma unroll
            for (int t = 0; t < 8; t++) {
                const float v = acc[t][r];
                s += v; s2 += v * v;
            }
            s += __shfl_xor(s, 1);  s2 += __shfl_xor(s2, 1);
            s += __shfl_xor(s, 2);  s2 += __shfl_xor(s2, 2);
            s += __shfl_xor(s, 4);  s2 += __shfl_xor(s2, 4);
            s += __shfl_xor(s, 8);  s2 += __shfl_xor(s2, 8);
            if (l16 == 0) {
                redS[wave][quad * 4 + r] = s;
                redS2[wave][quad * 4 + r] = s2;
            }
        }
    }
    __syncthreads();
    if (tid < 16) {
        const float S  = redS[0][tid] + redS[1][tid];
        const float S2 = redS2[0][tid] + redS2[1][tid];
        const float mu = S * (1.f / D);
        float var = S2 * (1.f / D) - mu * mu;
        var = fmaxf(var, 0.f);
        muA[tid] = mu;
        rsA[tid] = rsqrtf(var + LN_EPS);
    }
    __syncthreads();

    if (wave < 2) {
#pragma unroll
        for (int r = 0; r < 4; r++) {
            const int rl = quad * 4 + r;
            const int rg = row0 + rl;
            const float mu = muA[rl];
            const float rs = rsA[rl];
#pragma unroll
            for (int t = 0; t < 8; t++) {
                const int col = wave * 128 + t * 16 + l16;
                float o = (acc[t][r] - mu) * rs * gamma[col] + beta[col];
                o = fmaxf(o, 0.f);
                if (out_f) out_f[(size_t)rg * D + col] = o;
                else       out_b[(size_t)rg * D + col] = f2b(o);
            }
        }
    }
}

extern "C" void kernel_launch(void* const* d_in, const int* in_sizes, int n_in,
                              void* d_out, int out_size, void* d_ws, size_t ws_size,
                              hipStream_t stream) {
    const float* h    = (const float*)d_in[0];
    const int*   esrc = (const int*)d_in[1];
    const int*   edst = (const int*)d_in[2];
    const float* Wp0  = (const float*)d_in[3];
    const float* bp0  = (const float*)d_in[4];
    const float* Ws0  = (const float*)d_in[5];
    const float* Wn0  = (const float*)d_in[6];
    const float* b0   = (const float*)d_in[7];
    const float* g0   = (const float*)d_in[8];
    const float* be0  = (const float*)d_in[9];
    const float* Wp1  = (const float*)d_in[10];
    const float* bp1  = (const float*)d_in[11];
    const float* Ws1  = (const float*)d_in[12];
    const float* Wn1  = (const float*)d_in[13];
    const float* b1   = (const float*)d_in[14];
    const float* g1   = (const float*)d_in[15];
    const float* be1  = (const float*)d_in[16];

    const int N = in_sizes[0] / D;   // 10000 (fits ushort index space)
    const int E = in_sizes[1];       // 320000
    const size_t ND = (size_t)N * D;

    unsigned short* mb  = (unsigned short*)d_ws;        // N+1 rows (row N = pad)
    unsigned short* h1b = mb + ND + D;
    unsigned short* wb  = h1b + ND;                     // 6 * 65536 bf16
    int* cnt = (int*)(wb + 6 * 65536);                  // N
    unsigned short* csr = (unsigned short*)(cnt + N);   // N * CAP ushort

    unsigned short* wpb0 = wb + 0 * 65536;
    unsigned short* wsb0 = wb + 1 * 65536;
    unsigned short* wnb0 = wb + 2 * 65536;
    unsigned short* wpb1 = wb + 3 * 65536;
    unsigned short* wsb1 = wb + 4 * 65536;
    unsigned short* wnb1 = wb + 5 * 65536;

    const int nrow = N / 16;                     // 625 row-blocks
    const int rblocks = ((nrow + 7) / 8) * 32;   // 2528
    const int pblocks = nrow;                    // 625 lnpool blocks
    const int sblocks = 1024;                    // scatter blocks fused into relu L0

    prep_kernel<<<425, 256, 0, stream>>>(Wp0, Ws0, Wn0, Wp1, Ws1, Wn1, wb,
                                         cnt, mb, N);

    // ---- layer 0 (gemm + scatter fused; A = h fp32, converted in-flight) ----
    gemm_relu<<<rblocks + sblocks, 64, 0, stream>>>(h, nullptr, wpb0, bp0, mb, nrow,
                                                    esrc, edst, cnt, csr, E, rblocks);
    gemm_ln_pool<<<pblocks, 384, 0, stream>>>(h, nullptr, wsb0, wnb0, mb, cnt, csr,
                                              b0, g0, be0, h1b, nullptr, N);

    // ---- layer 1 ----
    gemm_relu<<<rblocks, 64, 0, stream>>>(nullptr, h1b, wpb1, bp1, mb, nrow,
                                          esrc, edst, cnt, csr, 0, rblocks);
    gemm_ln_pool<<<pblocks, 384, 0, stream>>>(nullptr, h1b, wsb1, wnb1, mb, cnt, csr,
                                              b1, g1, be1, nullptr, (float*)d_out, N);
}

// Round 13
// 212.550 us; speedup vs baseline: 1.0438x; 1.0438x over previous
//
#include <hip/hip_runtime.h>

#define D 256
#define CAP 128          // max stored neighbors/node; deg ~ Binom(320k,1e-4): mean 32, >15 sigma margin
#define ASTRIDE 280      // LDS agg row stride in bf16 (560 B -> bank rotation, ~free)
#define LN_EPS 1e-5f

typedef short short8 __attribute__((ext_vector_type(8)));
typedef float floatx4 __attribute__((ext_vector_type(4)));
typedef unsigned short u16x4 __attribute__((ext_vector_type(4)));

typedef const __attribute__((address_space(1))) void* gas_t;
typedef __attribute__((address_space(3))) void* las_t;

// s_waitcnt vmcnt(n), lgkm/exp don't-care
#define WAIT_VM(n) __builtin_amdgcn_s_waitcnt(((n) & 0xF) | (((n) >> 4) << 14) | (7 << 4) | (0xF << 8))

__device__ __forceinline__ u16x4 umax4(u16x4 a, u16x4 b) {
#if __has_builtin(__builtin_elementwise_max)
    return __builtin_elementwise_max(a, b);   // v_pk_max_u16 x2
#else
    u16x4 r;
    r.x = a.x > b.x ? a.x : b.x; r.y = a.y > b.y ? a.y : b.y;
    r.z = a.z > b.z ? a.z : b.z; r.w = a.w > b.w ? a.w : b.w;
    return r;
#endif
}

// fp32 -> bf16 round-to-nearest-even (finite inputs)
__device__ __forceinline__ unsigned short f2b(float f) {
    union { float f; unsigned int u; } x; x.f = f;
    unsigned int u = x.u + 0x7FFFu + ((x.u >> 16) & 1u);
    return (unsigned short)(u >> 16);
}

// GEMM half-K pass: hoist 4 A-frags + 16 B-frags before the MFMAs.
#define GEMM_HALF(APTR_EXPR, WPTR, K0H)                                         \
    {                                                                           \
        short8 aF[4], bF[4][4];                                                 \
        _Pragma("unroll") for (int ks = 0; ks < 4; ks++)                        \
            aF[ks] = APTR_EXPR(K0H + ks * 32);                                  \
        _Pragma("unroll") for (int ks = 0; ks < 4; ks++)                        \
        _Pragma("unroll") for (int t = 0; t < 4; t++)                           \
            bF[ks][t] = *(const short8*)((WPTR) + t * 16 * D + (K0H) + ks * 32);\
        _Pragma("unroll") for (int ks = 0; ks < 4; ks++) {                      \
            acc[0] = __builtin_amdgcn_mfma_f32_16x16x32_bf16(aF[ks], bF[ks][0], acc[0], 0, 0, 0); \
            acc[1] = __builtin_amdgcn_mfma_f32_16x16x32_bf16(aF[ks], bF[ks][1], acc[1], 0, 0, 0); \
            acc[2] = __builtin_amdgcn_mfma_f32_16x16x32_bf16(aF[ks], bF[ks][2], acc[2], 0, 0, 0); \
            acc[3] = __builtin_amdgcn_mfma_f32_16x16x32_bf16(aF[ks], bF[ks][3], acc[3], 0, 0, 0); \
        }                                                                       \
    }

// ---------------- prep: weight conv + h conv + zero cnt + zero pad-row -------
__global__ __launch_bounds__(256) void prep_kernel(
    const float* __restrict__ w0, const float* __restrict__ w1,
    const float* __restrict__ w2, const float* __restrict__ w3,
    const float* __restrict__ w4, const float* __restrict__ w5,
    unsigned short* __restrict__ wb,
    const float* __restrict__ h, unsigned short* __restrict__ hb, int nh4,
    int* __restrict__ cnt, unsigned short* __restrict__ mb, int N)
{
    const int blk = blockIdx.x;
    const int tid = threadIdx.x;
    if (blk < 384) {
        const int wsel = blk >> 6;
        const float* src;
        switch (wsel) {
            case 0: src = w0; break; case 1: src = w1; break;
            case 2: src = w2; break; case 3: src = w3; break;
            case 4: src = w4; break; default: src = w5; break;
        }
        const int idx = (blk & 63) * 1024 + tid * 4;
        const float4 v = *(const float4*)(src + idx);
        ushort4 o;
        o.x = f2b(v.x); o.y = f2b(v.y); o.z = f2b(v.z); o.w = f2b(v.w);
        *(ushort4*)(wb + (size_t)wsel * 65536 + idx) = o;
    } else if (blk < 1024) {
        int i = (blk - 384) * 256 + tid;
        const int stride = 640 * 256;
        for (; i < nh4; i += stride) {
            const float4 v = *(const float4*)(h + (size_t)i * 4);
            ushort4 o;
            o.x = f2b(v.x); o.y = f2b(v.y); o.z = f2b(v.z); o.w = f2b(v.w);
            *(ushort4*)(hb + (size_t)i * 4) = o;
        }
    } else if (blk < 1064) {
        const int i = (blk - 1024) * 256 + tid;
        if (i < N) cnt[i] = 0;
    } else {
        mb[(size_t)N * D + tid] = 0;   // pad row: max-identity for relu outputs
    }
}

// ---------------- mode-0 GEMM: 1-wave blocks for TLP (+ scatter blocks) ------
__global__ __launch_bounds__(64, 4) void gemm_relu(
    const unsigned short* __restrict__ A, const unsigned short* __restrict__ W,
    const float* __restrict__ bias, unsigned short* __restrict__ out_b, int N,
    const int* __restrict__ esrc, const int* __restrict__ edst,
    int* __restrict__ cnt, unsigned short* __restrict__ csr, int E, int ngemm)
{
    if ((int)blockIdx.x >= ngemm) {
        const int nsb = gridDim.x - ngemm;
        int i = ((int)blockIdx.x - ngemm) * 64 + threadIdx.x;
        const int stride = nsb * 64;
        for (; i < E; i += stride) {
            const int d = edst[i];
            const int pos = atomicAdd(&cnt[d], 1);
            if (pos < CAP) csr[(size_t)d * CAP + pos] = (unsigned short)esrc[i];
        }
        return;
    }

    const int lane = threadIdx.x;
    const int quad = lane >> 4;
    const int l16 = lane & 15;
    const int blk = blockIdx.x;
    const int row0 = (blk >> 2) * 16;       // consecutive blocks share A rows
    const int col0 = (blk & 3) * 64;
    const int koff = quad * 8;

    floatx4 acc[4];
#pragma unroll
    for (int t = 0; t < 4; t++) acc[t] = (floatx4)(0.f);

    const unsigned short* aptr = A + (size_t)(row0 + l16) * D + koff;
    const unsigned short* wptr = W + (size_t)(col0 + l16) * D + koff;
#define A_GLOBAL(K) (*(const short8*)(aptr + (K)))
    GEMM_HALF(A_GLOBAL, wptr, 0)
    GEMM_HALF(A_GLOBAL, wptr, 128)
#undef A_GLOBAL

#pragma unroll
    for (int t = 0; t < 4; t++) {
        const float bcol = bias[col0 + t * 16 + l16];
#pragma unroll
        for (int r = 0; r < 4; r++) {
            const int rg = row0 + quad * 4 + r;
            const int col = col0 + t * 16 + l16;
            out_b[(size_t)rg * D + col] = f2b(fmaxf(acc[t][r] + bcol, 0.f));
        }
    }
}

// ---------------- mode-1 GEMM with fused async pooling (+opt next-layer m) ---
// out = relu(LN(A@Wself^T + pool_max(mpool)@Wneigh^T + bias)*gamma + beta)
// If Wnext != null, a phase 2 computes mout = relu(out @ Wnext^T + bnext) for
// this block's 16 rows (tile parked in aggS after LN) — eliminates the whole
// next-layer gemm_relu dispatch. Pool internals frozen at R8/R10 optimum.
__global__ __launch_bounds__(256, 3) void gemm_ln_pool(
    const unsigned short* __restrict__ A, const unsigned short* __restrict__ Wself,
    const unsigned short* __restrict__ Wneigh,
    const unsigned short* __restrict__ mpool,
    const int* __restrict__ cnt, const unsigned short* __restrict__ csr,
    const float* __restrict__ bias,
    const float* __restrict__ gamma, const float* __restrict__ beta,
    unsigned short* __restrict__ out_b, float* __restrict__ out_f,
    const unsigned short* __restrict__ Wnext, const float* __restrict__ bnext,
    unsigned short* __restrict__ mout, int N)
{
    __shared__ unsigned short idxS[16][CAP];          // 4 KB
    __shared__ unsigned short gbuf[4][2][8][D];       // 32 KB
    __shared__ unsigned short aggS[16 * ASTRIDE];     // ~9 KB (pool agg, then out tile)
    __shared__ float redS[4][16], redS2[4][16], muA[16], rsA[16];

    const int tid = threadIdx.x;
    const int wave = tid >> 6;
    const int lane = tid & 63;
    const int quad = lane >> 4;
    const int l16 = lane & 15;
    const int row0 = blockIdx.x * 16;
    const int koff = quad * 8;
    const int rbase = wave * 4;
    const int half = lane >> 5;       // 0: lanes 0-31, 1: lanes 32-63
    const int l32 = lane & 31;

    // ---- stage neighbor indices into LDS (pad to even with zero-row N) ----
    int degs[4];
#pragma unroll
    for (int rr = 0; rr < 4; rr++) degs[rr] = min(cnt[row0 + rbase + rr], CAP);
    int P = max(max(degs[0], degs[1]), max(degs[2], degs[3]));
    const int P2 = (P + 1) & ~1;                      // <= CAP
#pragma unroll
    for (int rr = 0; rr < 4; rr++) {
        const int rg = row0 + rbase + rr;
        for (int i = lane; i < P2; i += 64)
            idxS[rbase + rr][i] = (i < degs[rr]) ? csr[(size_t)rg * CAP + i]
                                                 : (unsigned short)N;
    }

    floatx4 acc[4];
#pragma unroll
    for (int t = 0; t < 4; t++) acc[t] = (floatx4)(0.f);

    // ---- phase 0: A @ Wself ----
    {
        const unsigned short* aptr = A + (size_t)(row0 + l16) * D + koff;
        const unsigned short* wptr = Wself + (size_t)(wave * 64 + l16) * D + koff;
#pragma unroll
        for (int k0 = 0; k0 < D; k0 += 32) {
            const short8 av = *(const short8*)(aptr + k0);
            const short8 b0 = *(const short8*)(wptr + k0);
            const short8 b1 = *(const short8*)(wptr + 16 * D + k0);
            const short8 b2 = *(const short8*)(wptr + 32 * D + k0);
            const short8 b3 = *(const short8*)(wptr + 48 * D + k0);
            acc[0] = __builtin_amdgcn_mfma_f32_16x16x32_bf16(av, b0, acc[0], 0, 0, 0);
            acc[1] = __builtin_amdgcn_mfma_f32_16x16x32_bf16(av, b1, acc[1], 0, 0, 0);
            acc[2] = __builtin_amdgcn_mfma_f32_16x16x32_bf16(av, b2, acc[2], 0, 0, 0);
            acc[3] = __builtin_amdgcn_mfma_f32_16x16x32_bf16(av, b3, acc[3], 0, 0, 0);
        }
    }

    // ---- pool: async gather bursts, double-buffered, 8 KB/wave in flight ----
    {
        const int nb = P2 >> 1;       // bursts; each covers 2 neighbors per rr
        u16x4 mx[4];
#pragma unroll
        for (int rr = 0; rr < 4; rr++) mx[rr] = (u16x4)(0);

#define ISSUE_BURST(bi, buf)                                                    \
        {                                                                       \
            _Pragma("unroll") for (int rr = 0; rr < 4; rr++) {                  \
                const int jj = idxS[rbase + rr][2 * (bi) + half];               \
                const unsigned short* gp = mpool + (size_t)jj * D + l32 * 8;    \
                __builtin_amdgcn_global_load_lds(                               \
                    (gas_t)gp, (las_t)&gbuf[wave][buf][rr * 2][0], 16, 0, 0);   \
            }                                                                   \
        }

        if (nb > 0) ISSUE_BURST(0, 0);
        if (nb > 1) ISSUE_BURST(1, 1);
        for (int b = 0; b < nb; b++) {
            if (b + 1 < nb) WAIT_VM(4); else WAIT_VM(0);
            const int buf = b & 1;
#pragma unroll
            for (int rr = 0; rr < 4; rr++) {
                const u16x4 a0 = *(const u16x4*)&gbuf[wave][buf][rr * 2 + 0][lane * 4];
                const u16x4 a1 = *(const u16x4*)&gbuf[wave][buf][rr * 2 + 1][lane * 4];
                mx[rr] = umax4(mx[rr], umax4(a0, a1));
            }
            if (b + 2 < nb) ISSUE_BURST(b + 2, buf);
        }
#undef ISSUE_BURST
#pragma unroll
        for (int rr = 0; rr < 4; rr++)
            *(u16x4*)&aggS[(rbase + rr) * ASTRIDE + lane * 4] = mx[rr];
    }
    __syncthreads();

    // ---- phase 1: agg @ Wneigh (A-fragments from LDS) ----
    {
        const unsigned short* wptr = Wneigh + (size_t)(wave * 64 + l16) * D + koff;
#pragma unroll
        for (int k0 = 0; k0 < D; k0 += 32) {
            const short8 av = *(const short8*)&aggS[l16 * ASTRIDE + koff + k0];
            const short8 b0 = *(const short8*)(wptr + k0);
            const short8 b1 = *(const short8*)(wptr + 16 * D + k0);
            const short8 b2 = *(const short8*)(wptr + 32 * D + k0);
            const short8 b3 = *(const short8*)(wptr + 48 * D + k0);
            acc[0] = __builtin_amdgcn_mfma_f32_16x16x32_bf16(av, b0, acc[0], 0, 0, 0);
            acc[1] = __builtin_amdgcn_mfma_f32_16x16x32_bf16(av, b1, acc[1], 0, 0, 0);
            acc[2] = __builtin_amdgcn_mfma_f32_16x16x32_bf16(av, b2, acc[2], 0, 0, 0);
            acc[3] = __builtin_amdgcn_mfma_f32_16x16x32_bf16(av, b3, acc[3], 0, 0, 0);
        }
    }

    // ---- bias ----
    float bcol[4];
#pragma unroll
    for (int t = 0; t < 4; t++) bcol[t] = bias[wave * 64 + t * 16 + l16];
#pragma unroll
    for (int t = 0; t < 4; t++)
#pragma unroll
        for (int r = 0; r < 4; r++) acc[t][r] += bcol[t];

    // ---- LayerNorm reduction ----
#pragma unroll
    for (int r = 0; r < 4; r++) {
        float s = 0.f, s2 = 0.f;
#pragma unroll
        for (int t = 0; t < 4; t++) {
            const float v = acc[t][r];
            s += v; s2 += v * v;
        }
        s += __shfl_xor(s, 1);  s2 += __shfl_xor(s2, 1);
        s += __shfl_xor(s, 2);  s2 += __shfl_xor(s2, 2);
        s += __shfl_xor(s, 4);  s2 += __shfl_xor(s2, 4);
        s += __shfl_xor(s, 8);  s2 += __shfl_xor(s2, 8);
        if (l16 == 0) {
            redS[wave][quad * 4 + r] = s;
            redS2[wave][quad * 4 + r] = s2;
        }
    }
    __syncthreads();
    if (tid < 16) {
        const float S  = redS[0][tid] + redS[1][tid] + redS[2][tid] + redS[3][tid];
        const float S2 = redS2[0][tid] + redS2[1][tid] + redS2[2][tid] + redS2[3][tid];
        const float mu = S * (1.f / D);
        float var = S2 * (1.f / D) - mu * mu;
        var = fmaxf(var, 0.f);
        muA[tid] = mu;
        rsA[tid] = rsqrtf(var + LN_EPS);
    }
    __syncthreads();

    float gcol[4], becol[4];
#pragma unroll
    for (int t = 0; t < 4; t++) {
        gcol[t] = gamma[wave * 64 + t * 16 + l16];
        becol[t] = beta[wave * 64 + t * 16 + l16];
    }
#pragma unroll
    for (int r = 0; r < 4; r++) {
        const int rl = quad * 4 + r;
        const int rg = row0 + rl;
        const float mu = muA[rl];
        const float rs = rsA[rl];
#pragma unroll
        for (int t = 0; t < 4; t++) {
            const int col = wave * 64 + t * 16 + l16;
            float o = (acc[t][r] - mu) * rs * gcol[t] + becol[t];
            o = fmaxf(o, 0.f);
            const unsigned short ob = f2b(o);
            if (out_f) out_f[(size_t)rg * D + col] = o;
            else       out_b[(size_t)rg * D + col] = ob;
            if (Wnext) aggS[rl * ASTRIDE + col] = ob;   // park tile for phase 2
        }
    }

    // ---- phase 2 (optional): mout = relu(out_tile @ Wnext^T + bnext) ----
    if (Wnext) {
        __syncthreads();   // tile fully written
#pragma unroll
        for (int t = 0; t < 4; t++) acc[t] = (floatx4)(0.f);
        const unsigned short* wptr = Wnext + (size_t)(wave * 64 + l16) * D + koff;
#pragma unroll
        for (int k0 = 0; k0 < D; k0 += 32) {
            const short8 av = *(const short8*)&aggS[l16 * ASTRIDE + koff + k0];
            const short8 b0 = *(const short8*)(wptr + k0);
            const short8 b1 = *(const short8*)(wptr + 16 * D + k0);
            const short8 b2 = *(const short8*)(wptr + 32 * D + k0);
            const short8 b3 = *(const short8*)(wptr + 48 * D + k0);
            acc[0] = __builtin_amdgcn_mfma_f32_16x16x32_bf16(av, b0, acc[0], 0, 0, 0);
            acc[1] = __builtin_amdgcn_mfma_f32_16x16x32_bf16(av, b1, acc[1], 0, 0, 0);
            acc[2] = __builtin_amdgcn_mfma_f32_16x16x32_bf16(av, b2, acc[2], 0, 0, 0);
            acc[3] = __builtin_amdgcn_mfma_f32_16x16x32_bf16(av, b3, acc[3], 0, 0, 0);
        }
#pragma unroll
        for (int t = 0; t < 4; t++) {
            const float bc = bnext[wave * 64 + t * 16 + l16];
#pragma unroll
            for (int r = 0; r < 4; r++) {
                const int rg = row0 + quad * 4 + r;
                const int col = wave * 64 + t * 16 + l16;
                mout[(size_t)rg * D + col] = f2b(fmaxf(acc[t][r] + bc, 0.f));
            }
        }
    }
}

extern "C" void kernel_launch(void* const* d_in, const int* in_sizes, int n_in,
                              void* d_out, int out_size, void* d_ws, size_t ws_size,
                              hipStream_t stream) {
    const float* h    = (const float*)d_in[0];
    const int*   esrc = (const int*)d_in[1];
    const int*   edst = (const int*)d_in[2];
    const float* Wp0  = (const float*)d_in[3];
    const float* bp0  = (const float*)d_in[4];
    const float* Ws0  = (const float*)d_in[5];
    const float* Wn0  = (const float*)d_in[6];
    const float* b0   = (const float*)d_in[7];
    const float* g0   = (const float*)d_in[8];
    const float* be0  = (const float*)d_in[9];
    const float* Wp1  = (const float*)d_in[10];
    const float* bp1  = (const float*)d_in[11];
    const float* Ws1  = (const float*)d_in[12];
    const float* Wn1  = (const float*)d_in[13];
    const float* b1   = (const float*)d_in[14];
    const float* g1   = (const float*)d_in[15];
    const float* be1  = (const float*)d_in[16];

    const int N = in_sizes[0] / D;   // 10000 (fits ushort index space)
    const int E = in_sizes[1];       // 320000
    const size_t ND = (size_t)N * D;

    unsigned short* hb  = (unsigned short*)d_ws;
    unsigned short* mb  = hb + ND;           // N+1 rows (row N = gather pad)
    unsigned short* h1b = mb + ND + D;
    unsigned short* wb  = h1b + ND;          // 6 * 65536 bf16
    int* cnt = (int*)(wb + 6 * 65536);       // N
    unsigned short* csr = (unsigned short*)(cnt + N);   // N * CAP ushort

    unsigned short* wpb0 = wb + 0 * 65536;
    unsigned short* wsb0 = wb + 1 * 65536;
    unsigned short* wnb0 = wb + 2 * 65536;
    unsigned short* wpb1 = wb + 3 * 65536;
    unsigned short* wsb1 = wb + 4 * 65536;
    unsigned short* wnb1 = wb + 5 * 65536;

    const int rblocks = (N / 16) * 4;        // 2500 one-wave GEMM blocks
    const int pblocks = N / 16;              // 625 lnpool blocks
    const int sblocks = 1024;                // scatter blocks fused into relu L0

    prep_kernel<<<1065, 256, 0, stream>>>(Wp0, Ws0, Wn0, Wp1, Ws1, Wn1, wb,
                                          h, hb, (int)(ND / 4), cnt, mb, N);

    // ---- layer 0 (gemm + scatter fused) ----
    gemm_relu<<<rblocks + sblocks, 64, 0, stream>>>(hb, wpb0, bp0, mb, N,
                                                    esrc, edst, cnt, csr, E, rblocks);
    // lnpool L0 also produces m1 = relu(h1 @ Wp1^T + bp1) (phase 2) -> no relu L1
    gemm_ln_pool<<<pblocks, 256, 0, stream>>>(hb, wsb0, wnb0, mb, cnt, csr,
                                              b0, g0, be0, h1b, nullptr,
                                              wpb1, bp1, mb, N);

    // ---- layer 1 ----
    gemm_ln_pool<<<pblocks, 256, 0, stream>>>(h1b, wsb1, wnb1, mb, cnt, csr,
                                              b1, g1, be1, nullptr, (float*)d_out,
                                              nullptr, nullptr, nullptr, N);
}